// Round 15
// baseline (227.955 us; speedup 1.0000x reference)
//
#include <hip/hip_runtime.h>
#include <hip/hip_bf16.h>

// FlashSVDFFN: out = (gelu((x@U1)@V1 + b1)@U2)@V2 + b2
// packall: weight repacks (u2: pi k-slot perm, chunked [D_FF/32][256][32], NO swizzle)
// pgemm:   P = bf16(x)@U1  [16384][256] bf16
// hqgemm:  fused H+Q pipelined Q(c-1)||H(c); v1 LDS-staged (DMA 1-ahead),
//          u2 fragments read DIRECT from global (1KB/wave contiguous, L1/L2 broadcast).
// ogemm:   out = (sum_j qpart_j)@V2 + b2

typedef __attribute__((ext_vector_type(8))) short bfrag8;     // 8 bf16 fragment
typedef __attribute__((ext_vector_type(4))) float fx4;
typedef __attribute__((ext_vector_type(4))) unsigned short usx4;

#define D_MODEL 1024
#define D_FF    4096
#define RANK    256
#define NROWS   16384
#define PSTR    264        // ogemm LDS stride (256+8)
#define XSTR    136        // pgemm LDS stride (128+8)

__device__ __forceinline__ unsigned short f2b(float f) {
  __hip_bfloat16 h = __float2bfloat16(f);
  unsigned short u; __builtin_memcpy(&u, &h, 2); return u;
}
__device__ __forceinline__ float b2f(unsigned short u) {
  union { unsigned u; float f; } v; v.u = ((unsigned)u) << 16; return v.f;
}

// gelu_tanh = x * sigmoid(1.59577(x + 0.044715 x^3))
__device__ __forceinline__ float gelu_tanh(float x) {
  float x2 = x * x;
  float inner = __builtin_fmaf(0.044715f * x2, x, x);
  float e = __builtin_amdgcn_exp2f(-2.302118885f * inner);
  return x * __builtin_amdgcn_rcpf(1.0f + e);
}

__device__ __forceinline__ void gl_lds16(const unsigned short* g, unsigned short* l) {
  __builtin_amdgcn_global_load_lds(
      (const __attribute__((address_space(1))) unsigned int*)g,
      (__attribute__((address_space(3))) unsigned int*)l, 16, 0, 0);
}

// ---- all four weight repacks, one launch, flat grid of 2560 32x32 tiles ----
__global__ void packall(const float* __restrict__ U1, const float* __restrict__ V1,
                        const float* __restrict__ U2, const float* __restrict__ V2,
                        unsigned short* __restrict__ u1t, unsigned short* __restrict__ v1c,
                        unsigned short* __restrict__ u2c, unsigned short* __restrict__ v2t) {
  __shared__ float t[32][33];
  const int b = blockIdx.x;
  const int tx = threadIdx.x & 31, ty = threadIdx.x >> 5;
  if (b < 256) {                       // U1 transpose
    int c0 = (b & 7) * 32, r0 = (b >> 3) * 32;
#pragma unroll
    for (int i = 0; i < 32; i += 8)
      t[ty + i][tx] = U1[(size_t)(r0 + ty + i) * RANK + c0 + tx];
    __syncthreads();
#pragma unroll
    for (int i = 0; i < 32; i += 8)
      u1t[(size_t)(c0 + ty + i) * D_MODEL + r0 + tx] = f2b(t[tx][ty + i]);
  } else if (b < 1280) {               // v1pack (bank-swizzled, unchanged)
    int tt = b - 256;
    int f0 = (tt & 127) * 32, k0 = (tt >> 7) * 32;
#pragma unroll
    for (int i = 0; i < 32; i += 8)
      t[ty + i][tx] = V1[(size_t)(k0 + ty + i) * D_FF + f0 + tx];   // t[k_l][f_l]
    __syncthreads();
#pragma unroll
    for (int i = 0; i < 32; i += 8) {
      int f = ty + i;
      v1c[(size_t)(f0 + f) * RANK + ((k0 + tx) ^ ((f & 7) << 3))] = f2b(t[tx][f]);
    }
  } else if (b < 2304) {               // u2pack: pi k-slot perm ONLY (no LDS swizzle)
    int tt = b - 1280;
    int f0 = (tt & 127) * 32, r0 = (tt >> 7) * 32, cg = tt & 127;
#pragma unroll
    for (int i = 0; i < 32; i += 8)
      t[ty + i][tx] = U2[(size_t)(f0 + ty + i) * RANK + r0 + tx];   // t[f_l][r2_l]
    __syncthreads();
#pragma unroll
    for (int i = 0; i < 32; i += 8) {
      int r2l = ty + i;
      int fl = (((tx & 7) >= 4) ? 16 : 0) + 4 * (tx >> 3) + (tx & 3);
      u2c[(size_t)cg * 8192 + (size_t)(r0 + r2l) * 32 + tx] = f2b(t[fl][r2l]);
    }
  } else {                             // V2 transpose
    int tt = b - 2304;
    int c0 = (tt & 31) * 32, r0 = (tt >> 5) * 32;
#pragma unroll
    for (int i = 0; i < 32; i += 8)
      t[ty + i][tx] = V2[(size_t)(r0 + ty + i) * D_MODEL + c0 + tx];
    __syncthreads();
#pragma unroll
    for (int i = 0; i < 32; i += 8)
      v2t[(size_t)(c0 + ty + i) * RANK + r0 + tx] = f2b(t[tx][ty + i]);
  }
}

// ---------------- P = bf16(x) @ U1 : [16384][256] bf16 ----------------
__global__ __launch_bounds__(256, 4) void pgemm(
    const float* __restrict__ x, const unsigned short* __restrict__ u1t,
    unsigned short* __restrict__ P)
{
  __shared__ unsigned short xs[32 * XSTR];
  const int tid = threadIdx.x;
  const int w = tid >> 6, lane = tid & 63, lo = lane & 15, hi = lane >> 4;
  const size_t gr0 = (size_t)blockIdx.x * 32;

  fx4 acc[2][4];
#pragma unroll
  for (int mt = 0; mt < 2; ++mt)
#pragma unroll
    for (int nt = 0; nt < 4; ++nt) acc[mt][nt] = fx4{0.f, 0.f, 0.f, 0.f};

  for (int d0 = 0; d0 < D_MODEL; d0 += 128) {
    __syncthreads();
#pragma unroll
    for (int it = 0; it < 4; ++it) {
      int idx = it * 256 + tid;
      int r = idx >> 5, c = (idx & 31) << 2;
      fx4 v = *(const fx4*)(x + (gr0 + r) * D_MODEL + d0 + c);
      usx4 bv; bv[0] = f2b(v[0]); bv[1] = f2b(v[1]); bv[2] = f2b(v[2]); bv[3] = f2b(v[3]);
      *(usx4*)(xs + r * XSTR + c) = bv;
    }
    __syncthreads();
#pragma unroll
    for (int ks = 0; ks < 128; ks += 32) {
      bfrag8 a[2], b[4];
#pragma unroll
      for (int mt = 0; mt < 2; ++mt)
        a[mt] = *(const bfrag8*)(xs + (16 * mt + lo) * XSTR + ks + hi * 8);
#pragma unroll
      for (int nt = 0; nt < 4; ++nt)
        b[nt] = *(const bfrag8*)(u1t + (size_t)(w * 64 + nt * 16 + lo) * D_MODEL + d0 + ks + hi * 8);
#pragma unroll
      for (int mt = 0; mt < 2; ++mt)
#pragma unroll
        for (int nt = 0; nt < 4; ++nt)
          acc[mt][nt] = __builtin_amdgcn_mfma_f32_16x16x32_bf16(a[mt], b[nt], acc[mt][nt], 0, 0, 0);
    }
  }
#pragma unroll
  for (int mt = 0; mt < 2; ++mt)
#pragma unroll
    for (int nt = 0; nt < 4; ++nt)
#pragma unroll
      for (int r = 0; r < 4; ++r)
        P[(gr0 + 16 * mt + 4 * hi + r) * RANK + w * 64 + nt * 16 + lo] = f2b(acc[mt][nt][r]);
}

// -------- fused H+Q pipelined; v1 via LDS DMA, u2 direct from global --------
// 256 thr = 4 waves, wave owns rows [rowstart, rowstart+32) x all 256 r2.
// Register-locked at 2 waves/SIMD — do NOT raise min-waves (r11 spill).
__global__ __launch_bounds__(256, 2) void hqgemm(
    const unsigned short* __restrict__ P,     // [NROWS][RANK] bf16
    const unsigned short* __restrict__ v1c,   // [D_FF][RANK] bf16 swizzled
    const float* __restrict__ b1,
    const unsigned short* __restrict__ u2c,   // [D_FF/32][256][32] bf16 pi-permuted
    unsigned short* __restrict__ qpart,       // [F][NROWS][RANK] bf16
    int F)
{
  __shared__ unsigned short v1s[2][32 * 256];   // 2 x 16 KB (only v1 staged now)
  __shared__ float b1s[1024];

  const int tid = threadIdx.x;
  const int w = tid >> 6, lane = tid & 63, lo = lane & 15, hi = lane >> 4;

  const int bid = blockIdx.x;
  const int j = bid % F;
  const int rb = bid / F;
  const int fspan = D_FF / F;
  const int fbase = j * fspan;
  const int nchunk = fspan / 32;
  const int rowstart = rb * 128 + w * 32;

  // ---- prologue global loads ----
  bfrag8 pf[2][8];
#pragma unroll
  for (int rg = 0; rg < 2; ++rg)
#pragma unroll
    for (int ks = 0; ks < 8; ++ks)
      pf[rg][ks] = *(const bfrag8*)(P + (size_t)(rowstart + 16 * rg + lo) * RANK + ks * 32 + hi * 8);
  for (int i = tid; i < fspan; i += 256) b1s[i] = b1[fbase + i];

  fx4 qacc[2][16];
#pragma unroll
  for (int rg = 0; rg < 2; ++rg)
#pragma unroll
    for (int nt = 0; nt < 16; ++nt) qacc[rg][nt] = fx4{0.f, 0.f, 0.f, 0.f};

  const int vswz = (lo & 7) << 3;
  const int vbase = lo * 256;
  const int qrow = hi * 8;          // u2 fragment sub-offset (no swizzle)

#define STAGE_V(C, B) do {                                                     \
    const unsigned short* s_ = v1c + (size_t)(fbase + (C) * 32) * 256;         \
    _Pragma("unroll")                                                          \
    for (int p = 0; p < 4; ++p) {                                              \
      int o_ = tid * 8 + p * 2048;                                             \
      gl_lds16(s_ + o_, &v1s[B][o_]);                                          \
    } } while (0)

  bfrag8 bq0, bq1;                  // persists across iterations

  STAGE_V(0, 0);
  __syncthreads();                  // drains pf/b1/V(0); b1s visible

  // ---- H(0) + gelu -> bq(0) ----
  if (nchunk > 1) STAGE_V(1, 1);    // fly during H(0)
  {
    const unsigned short* vb = v1s[0];
    fx4 hacc[2][2];
#pragma unroll
    for (int t = 0; t < 2; ++t)
#pragma unroll
      for (int rg = 0; rg < 2; ++rg) hacc[t][rg] = fx4{0.f, 0.f, 0.f, 0.f};
    __builtin_amdgcn_s_setprio(1);
#pragma unroll
    for (int ks = 0; ks < 8; ++ks) {
      int ko = (ks * 32 + hi * 8) ^ vswz;
      bfrag8 vE = *(const bfrag8*)(vb + vbase + ko);
      bfrag8 vO = *(const bfrag8*)(vb + vbase + 4096 + ko);
      hacc[0][0] = __builtin_amdgcn_mfma_f32_16x16x32_bf16(vE, pf[0][ks], hacc[0][0], 0, 0, 0);
      hacc[0][1] = __builtin_amdgcn_mfma_f32_16x16x32_bf16(vE, pf[1][ks], hacc[0][1], 0, 0, 0);
      hacc[1][0] = __builtin_amdgcn_mfma_f32_16x16x32_bf16(vO, pf[0][ks], hacc[1][0], 0, 0, 0);
      hacc[1][1] = __builtin_amdgcn_mfma_f32_16x16x32_bf16(vO, pf[1][ks], hacc[1][1], 0, 0, 0);
    }
    __builtin_amdgcn_s_setprio(0);
    fx4 bE = *(const fx4*)(&b1s[4 * hi]);
    fx4 bO = *(const fx4*)(&b1s[16 + 4 * hi]);
#pragma unroll
    for (int r = 0; r < 4; ++r) {
      bq0[r]     = (short)f2b(gelu_tanh(hacc[0][0][r] + bE[r]));
      bq0[r + 4] = (short)f2b(gelu_tanh(hacc[1][0][r] + bO[r]));
      bq1[r]     = (short)f2b(gelu_tanh(hacc[0][1][r] + bE[r]));
      bq1[r + 4] = (short)f2b(gelu_tanh(hacc[1][1][r] + bO[r]));
    }
  }

  // ---- main pipelined loop: iteration c does Q(c-1) and H(c) ----
  for (int c = 1; c <= nchunk; ++c) {
    __syncthreads();                 // compiler drains vmcnt: V(c) landed; readers of
                                     // v1s[(c-1)&1] done -> safe to overwrite below
    if (c + 1 < nchunk) STAGE_V(c + 1, (c + 1) & 1);

    // Q(c-1): u2 fragments DIRECT from global (contiguous 1KB/wave, L1/L2 broadcast)
    const unsigned short* ub = u2c + (size_t)((fbase >> 5) + (c - 1)) * 8192;
    __builtin_amdgcn_s_setprio(1);
#pragma unroll
    for (int nt = 0; nt < 16; ++nt) {
      bfrag8 qa = *(const bfrag8*)(ub + (16 * nt + lo) * 32 + qrow);
      qacc[0][nt] = __builtin_amdgcn_mfma_f32_16x16x32_bf16(qa, bq0, qacc[0][nt], 0, 0, 0);
      qacc[1][nt] = __builtin_amdgcn_mfma_f32_16x16x32_bf16(qa, bq1, qacc[1][nt], 0, 0, 0);
    }

    // H(c): independent of Q(c-1) — interleavable by the scheduler
    if (c < nchunk) {
      const unsigned short* vb = v1s[c & 1];
      fx4 hacc[2][2];
#pragma unroll
      for (int t = 0; t < 2; ++t)
#pragma unroll
        for (int rg = 0; rg < 2; ++rg) hacc[t][rg] = fx4{0.f, 0.f, 0.f, 0.f};
#pragma unroll
      for (int ks = 0; ks < 8; ++ks) {
        int ko = (ks * 32 + hi * 8) ^ vswz;
        bfrag8 vE = *(const bfrag8*)(vb + vbase + ko);
        bfrag8 vO = *(const bfrag8*)(vb + vbase + 4096 + ko);
        hacc[0][0] = __builtin_amdgcn_mfma_f32_16x16x32_bf16(vE, pf[0][ks], hacc[0][0], 0, 0, 0);
        hacc[0][1] = __builtin_amdgcn_mfma_f32_16x16x32_bf16(vE, pf[1][ks], hacc[0][1], 0, 0, 0);
        hacc[1][0] = __builtin_amdgcn_mfma_f32_16x16x32_bf16(vO, pf[0][ks], hacc[1][0], 0, 0, 0);
        hacc[1][1] = __builtin_amdgcn_mfma_f32_16x16x32_bf16(vO, pf[1][ks], hacc[1][1], 0, 0, 0);
      }
      __builtin_amdgcn_s_setprio(0);
      fx4 bE = *(const fx4*)(&b1s[c * 32 + 4 * hi]);
      fx4 bO = *(const fx4*)(&b1s[c * 32 + 16 + 4 * hi]);
#pragma unroll
      for (int r = 0; r < 4; ++r) {
        bq0[r]     = (short)f2b(gelu_tanh(hacc[0][0][r] + bE[r]));
        bq0[r + 4] = (short)f2b(gelu_tanh(hacc[1][0][r] + bO[r]));
        bq1[r]     = (short)f2b(gelu_tanh(hacc[0][1][r] + bE[r]));
        bq1[r + 4] = (short)f2b(gelu_tanh(hacc[1][1][r] + bO[r]));
      }
    } else {
      __builtin_amdgcn_s_setprio(0);
    }
  }
#undef STAGE_V

  // qacc[rg][nt] lane (lo,hi): Q[rowstart+16rg+lo][16nt+4hi+r] -> bf16 qpart
  unsigned short* qp = qpart + (size_t)j * NROWS * RANK;
#pragma unroll
  for (int rg = 0; rg < 2; ++rg) {
    size_t row = (size_t)(rowstart + 16 * rg + lo);
#pragma unroll
    for (int nt = 0; nt < 16; ++nt) {
      usx4 qv;
      qv[0] = f2b(qacc[rg][nt][0]); qv[1] = f2b(qacc[rg][nt][1]);
      qv[2] = f2b(qacc[rg][nt][2]); qv[3] = f2b(qacc[rg][nt][3]);
      *(usx4*)(qp + row * RANK + 16 * nt + 4 * hi) = qv;
    }
  }
}

// ---------------- out = (sum_j Qpart_j) @ V2 + b2 ----------------
// grid (256, 2), 512 thr; wave = 32 rows x 128 cols -> qpart read 2x.
__global__ __launch_bounds__(512, 4) void ogemm(
    const unsigned short* __restrict__ qpart, int F,   // [F][NROWS][RANK] bf16
    const unsigned short* __restrict__ v2t,            // [D_MODEL][RANK]
    const float* __restrict__ b2,
    float* __restrict__ out)
{
  __shared__ unsigned short Qs[64 * PSTR];
  const int tid = threadIdx.x;
  const int w = tid >> 6, lane = tid & 63, lo = lane & 15, hi = lane >> 4;
  const int wm = w >> 2, wn = w & 3;          // wave grid 2x4
  const size_t gr0 = (size_t)blockIdx.x * 64;
  const int n0 = blockIdx.y * 512 + wn * 128;

#pragma unroll
  for (int it = 0; it < 8; ++it) {
    int idx = it * 512 + tid;
    int r = idx >> 6, c = (idx & 63) << 2;
    float s0 = 0.f, s1 = 0.f, s2 = 0.f, s3 = 0.f;
    for (int jj = 0; jj < F; ++jj) {
      usx4 q = *(const usx4*)(qpart + (size_t)jj * NROWS * RANK + (gr0 + r) * RANK + c);
      s0 += b2f(q[0]); s1 += b2f(q[1]); s2 += b2f(q[2]); s3 += b2f(q[3]);
    }
    usx4 bv; bv[0] = f2b(s0); bv[1] = f2b(s1); bv[2] = f2b(s2); bv[3] = f2b(s3);
    *(usx4*)(Qs + r * PSTR + c) = bv;
  }
  __syncthreads();

  fx4 acc[2][8];
#pragma unroll
  for (int mt = 0; mt < 2; ++mt)
#pragma unroll
    for (int nt = 0; nt < 8; ++nt) acc[mt][nt] = fx4{0.f, 0.f, 0.f, 0.f};

#pragma unroll
  for (int ks = 0; ks < RANK; ks += 32) {
    bfrag8 a[2], b[8];
#pragma unroll
    for (int mt = 0; mt < 2; ++mt)
      a[mt] = *(const bfrag8*)(Qs + (wm * 32 + 16 * mt + lo) * PSTR + ks + hi * 8);
#pragma unroll
    for (int nt = 0; nt < 8; ++nt)
      b[nt] = *(const bfrag8*)(v2t + (size_t)(n0 + nt * 16 + lo) * RANK + ks + hi * 8);
#pragma unroll
    for (int mt = 0; mt < 2; ++mt)
#pragma unroll
      for (int nt = 0; nt < 8; ++nt)
        acc[mt][nt] = __builtin_amdgcn_mfma_f32_16x16x32_bf16(a[mt], b[nt], acc[mt][nt], 0, 0, 0);
  }

#pragma unroll
  for (int nt = 0; nt < 8; ++nt) {
    int col = n0 + nt * 16 + lo;
    float bias = b2[col];
#pragma unroll
    for (int mt = 0; mt < 2; ++mt)
#pragma unroll
      for (int r = 0; r < 4; ++r)
        out[(gr0 + wm * 32 + 16 * mt + 4 * hi + r) * D_MODEL + col] = acc[mt][nt][r] + bias;
  }
}

extern "C" void kernel_launch(void* const* d_in, const int* in_sizes, int n_in,
                              void* d_out, int out_size, void* d_ws, size_t ws_size,
                              hipStream_t stream) {
  const float* x  = (const float*)d_in[0];
  const float* U1 = (const float*)d_in[1];
  const float* V1 = (const float*)d_in[2];
  const float* b1 = (const float*)d_in[3];
  const float* U2 = (const float*)d_in[4];
  const float* V2 = (const float*)d_in[5];
  const float* b2 = (const float*)d_in[6];
  float* out = (float*)d_out;

  unsigned short* ws16 = (unsigned short*)d_ws;
  unsigned short* u1t = ws16;                                 // [256][1024]
  unsigned short* v1c = u1t + (size_t)RANK * D_MODEL;         // [4096][256] swz
  unsigned short* u2c = v1c + (size_t)D_FF * RANK;            // [128][256][32] pi-perm
  unsigned short* v2t = u2c + (size_t)RANK * D_FF;            // [1024][256]
  unsigned short* Pbf = v2t + (size_t)D_MODEL * RANK;         // [16384][256] bf16
  unsigned short* qpart = Pbf + (size_t)NROWS * RANK;         // [F][16384][256] bf16

  size_t fixed_bytes = 2ull * ((size_t)RANK * D_MODEL + (size_t)D_FF * RANK +
                               (size_t)RANK * D_FF + (size_t)D_MODEL * RANK +
                               (size_t)NROWS * RANK);
  size_t qb = (size_t)NROWS * RANK * 2;   // bf16 slice
  int F = (ws_size >= fixed_bytes + 4 * qb) ? 4 : 2;

  packall<<<2560, 256, 0, stream>>>(U1, V1, U2, V2, u1t, v1c, u2c, v2t);
  pgemm<<<NROWS / 32, 256, 0, stream>>>(x, u1t, Pbf);
  hqgemm<<<(NROWS / 128) * F, 256, 0, stream>>>(Pbf, v1c, b1, u2c, qpart, F);
  ogemm<<<dim3(NROWS / 64, D_MODEL / 512), 512, 0, stream>>>(qpart, F, v2t, b2, out);
}

// Round 16
// 173.339 us; speedup vs baseline: 1.3151x; 1.3151x over previous
//
#include <hip/hip_runtime.h>
#include <hip/hip_bf16.h>

// FlashSVDFFN: out = (gelu((x@U1)@V1 + b1)@U2)@V2 + b2
// packall: weight repacks (u2 with pi k-slot perm + qoff swizzle)
// pgemm:   P = bf16(x)@U1  [16384][256] bf16
// hqgemm:  fused H+Q, swapped-operand MFMA; SOFTWARE-PIPELINED: Q(c-1) || H(c),
//          both operand streams LDS-staged, counted-vmcnt DMA (r14 structure).
// ogemm:   out = (sum_j qpart_j)@V2 + b2 (16B qpart loads)

typedef __attribute__((ext_vector_type(8))) short bfrag8;     // 8 bf16 fragment
typedef __attribute__((ext_vector_type(4))) float fx4;
typedef __attribute__((ext_vector_type(4))) unsigned short usx4;

#define D_MODEL 1024
#define D_FF    4096
#define RANK    256
#define NROWS   16384
#define PSTR    264        // ogemm LDS stride (256+8)
#define XSTR    136        // pgemm LDS stride (128+8)

__device__ __forceinline__ unsigned short f2b(float f) {
  __hip_bfloat16 h = __float2bfloat16(f);
  unsigned short u; __builtin_memcpy(&u, &h, 2); return u;
}
__device__ __forceinline__ float b2f(unsigned short u) {
  union { unsigned u; float f; } v; v.u = ((unsigned)u) << 16; return v.f;
}

// gelu_tanh = x * sigmoid(1.59577(x + 0.044715 x^3))
__device__ __forceinline__ float gelu_tanh(float x) {
  float x2 = x * x;
  float inner = __builtin_fmaf(0.044715f * x2, x, x);
  float e = __builtin_amdgcn_exp2f(-2.302118885f * inner);
  return x * __builtin_amdgcn_rcpf(1.0f + e);
}

__device__ __forceinline__ void gl_lds16(const unsigned short* g, unsigned short* l) {
  __builtin_amdgcn_global_load_lds(
      (const __attribute__((address_space(1))) unsigned int*)g,
      (__attribute__((address_space(3))) unsigned int*)l, 16, 0, 0);
}

// ---- all four weight repacks, one launch, flat grid of 2560 32x32 tiles ----
__global__ void packall(const float* __restrict__ U1, const float* __restrict__ V1,
                        const float* __restrict__ U2, const float* __restrict__ V2,
                        unsigned short* __restrict__ u1t, unsigned short* __restrict__ v1c,
                        unsigned short* __restrict__ u2c, unsigned short* __restrict__ v2t) {
  __shared__ float t[32][33];
  const int b = blockIdx.x;
  const int tx = threadIdx.x & 31, ty = threadIdx.x >> 5;
  if (b < 256) {                       // U1 transpose
    int c0 = (b & 7) * 32, r0 = (b >> 3) * 32;
#pragma unroll
    for (int i = 0; i < 32; i += 8)
      t[ty + i][tx] = U1[(size_t)(r0 + ty + i) * RANK + c0 + tx];
    __syncthreads();
#pragma unroll
    for (int i = 0; i < 32; i += 8)
      u1t[(size_t)(c0 + ty + i) * D_MODEL + r0 + tx] = f2b(t[tx][ty + i]);
  } else if (b < 1280) {               // v1pack (bank-swizzled)
    int tt = b - 256;
    int f0 = (tt & 127) * 32, k0 = (tt >> 7) * 32;
#pragma unroll
    for (int i = 0; i < 32; i += 8)
      t[ty + i][tx] = V1[(size_t)(k0 + ty + i) * D_FF + f0 + tx];   // t[k_l][f_l]
    __syncthreads();
#pragma unroll
    for (int i = 0; i < 32; i += 8) {
      int f = ty + i;
      v1c[(size_t)(f0 + f) * RANK + ((k0 + tx) ^ ((f & 7) << 3))] = f2b(t[tx][f]);
    }
  } else if (b < 2304) {               // u2pack (pi k-slot perm + swizzle)
    int tt = b - 1280;
    int f0 = (tt & 127) * 32, r0 = (tt >> 7) * 32, cg = tt & 127;
#pragma unroll
    for (int i = 0; i < 32; i += 8)
      t[ty + i][tx] = U2[(size_t)(f0 + ty + i) * RANK + r0 + tx];   // t[f_l][r2_l]
    __syncthreads();
#pragma unroll
    for (int i = 0; i < 32; i += 8) {
      int r2l = ty + i;
      int s = tx ^ (((r2l >> 1) & 3) << 3);
      int fl = (((s & 7) >= 4) ? 16 : 0) + 4 * (s >> 3) + (s & 3);
      u2c[(size_t)cg * 8192 + (size_t)(r0 + r2l) * 32 + tx] = f2b(t[fl][r2l]);
    }
  } else {                             // V2 transpose
    int tt = b - 2304;
    int c0 = (tt & 31) * 32, r0 = (tt >> 5) * 32;
#pragma unroll
    for (int i = 0; i < 32; i += 8)
      t[ty + i][tx] = V2[(size_t)(r0 + ty + i) * D_MODEL + c0 + tx];
    __syncthreads();
#pragma unroll
    for (int i = 0; i < 32; i += 8)
      v2t[(size_t)(c0 + ty + i) * RANK + r0 + tx] = f2b(t[tx][ty + i]);
  }
}

// ---------------- P = bf16(x) @ U1 : [16384][256] bf16 ----------------
__global__ __launch_bounds__(256, 4) void pgemm(
    const float* __restrict__ x, const unsigned short* __restrict__ u1t,
    unsigned short* __restrict__ P)
{
  __shared__ unsigned short xs[32 * XSTR];
  const int tid = threadIdx.x;
  const int w = tid >> 6, lane = tid & 63, lo = lane & 15, hi = lane >> 4;
  const size_t gr0 = (size_t)blockIdx.x * 32;

  fx4 acc[2][4];
#pragma unroll
  for (int mt = 0; mt < 2; ++mt)
#pragma unroll
    for (int nt = 0; nt < 4; ++nt) acc[mt][nt] = fx4{0.f, 0.f, 0.f, 0.f};

  for (int d0 = 0; d0 < D_MODEL; d0 += 128) {
    __syncthreads();
#pragma unroll
    for (int it = 0; it < 4; ++it) {
      int idx = it * 256 + tid;
      int r = idx >> 5, c = (idx & 31) << 2;
      fx4 v = *(const fx4*)(x + (gr0 + r) * D_MODEL + d0 + c);
      usx4 bv; bv[0] = f2b(v[0]); bv[1] = f2b(v[1]); bv[2] = f2b(v[2]); bv[3] = f2b(v[3]);
      *(usx4*)(xs + r * XSTR + c) = bv;
    }
    __syncthreads();
#pragma unroll
    for (int ks = 0; ks < 128; ks += 32) {
      bfrag8 a[2], b[4];
#pragma unroll
      for (int mt = 0; mt < 2; ++mt)
        a[mt] = *(const bfrag8*)(xs + (16 * mt + lo) * XSTR + ks + hi * 8);
#pragma unroll
      for (int nt = 0; nt < 4; ++nt)
        b[nt] = *(const bfrag8*)(u1t + (size_t)(w * 64 + nt * 16 + lo) * D_MODEL + d0 + ks + hi * 8);
#pragma unroll
      for (int mt = 0; mt < 2; ++mt)
#pragma unroll
        for (int nt = 0; nt < 4; ++nt)
          acc[mt][nt] = __builtin_amdgcn_mfma_f32_16x16x32_bf16(a[mt], b[nt], acc[mt][nt], 0, 0, 0);
    }
  }
#pragma unroll
  for (int mt = 0; mt < 2; ++mt)
#pragma unroll
    for (int nt = 0; nt < 4; ++nt)
#pragma unroll
      for (int r = 0; r < 4; ++r)
        P[(gr0 + 16 * mt + 4 * hi + r) * RANK + w * 64 + nt * 16 + lo] = f2b(acc[mt][nt][r]);
}

// -------- fused H+Q, software-pipelined: Q(c-1) || H(c) in each iteration --------
// 256 thr = 4 waves, wave owns rows [rowstart, rowstart+32) x all 256 r2.
// Register-locked at 2 waves/SIMD — do NOT raise min-waves (r11 spill).
__global__ __launch_bounds__(256, 2) void hqgemm(
    const unsigned short* __restrict__ P,     // [NROWS][RANK] bf16
    const unsigned short* __restrict__ v1c,   // [D_FF][RANK] bf16 swizzled
    const float* __restrict__ b1,
    const unsigned short* __restrict__ u2c,   // [D_FF/32][256][32] bf16 perm+swz
    unsigned short* __restrict__ qpart,       // [F][NROWS][RANK] bf16
    int F)
{
  __shared__ unsigned short v1s[2][32 * 256];   // 16 KB per buf
  __shared__ unsigned short u2s[2][256 * 32];   // 16 KB per buf
  __shared__ float b1s[1024];

  const int tid = threadIdx.x;
  const int w = tid >> 6, lane = tid & 63, lo = lane & 15, hi = lane >> 4;

  const int bid = blockIdx.x;
  const int j = bid % F;
  const int rb = bid / F;
  const int fspan = D_FF / F;
  const int fbase = j * fspan;
  const int nchunk = fspan / 32;
  const int rowstart = rb * 128 + w * 32;

  // ---- prologue global loads ----
  bfrag8 pf[2][8];
#pragma unroll
  for (int rg = 0; rg < 2; ++rg)
#pragma unroll
    for (int ks = 0; ks < 8; ++ks)
      pf[rg][ks] = *(const bfrag8*)(P + (size_t)(rowstart + 16 * rg + lo) * RANK + ks * 32 + hi * 8);
  for (int i = tid; i < fspan; i += 256) b1s[i] = b1[fbase + i];
  __syncthreads();                       // drains pf/b1 (vmcnt0), b1s visible

  fx4 qacc[2][16];
#pragma unroll
  for (int rg = 0; rg < 2; ++rg)
#pragma unroll
    for (int nt = 0; nt < 16; ++nt) qacc[rg][nt] = fx4{0.f, 0.f, 0.f, 0.f};

  const int vswz = (lo & 7) << 3;
  const int qoff = (hi * 8) ^ (((lo >> 1) & 3) << 3);
  const int vbase = lo * 256;

#define STAGE_V(C, B) do {                                                     \
    const unsigned short* s_ = v1c + (size_t)(fbase + (C) * 32) * 256;         \
    _Pragma("unroll")                                                          \
    for (int p = 0; p < 4; ++p) {                                              \
      int o_ = tid * 8 + p * 2048;                                             \
      gl_lds16(s_ + o_, &v1s[B][o_]);                                          \
    } } while (0)
#define STAGE_U(C, B) do {                                                     \
    const unsigned short* s_ = u2c + (size_t)((fbase >> 5) + (C)) * 8192;      \
    _Pragma("unroll")                                                          \
    for (int p = 0; p < 4; ++p) {                                              \
      int o_ = tid * 8 + p * 2048;                                             \
      gl_lds16(s_ + o_, &u2s[B][o_]);                                          \
    } } while (0)

  bfrag8 bq0, bq1;                      // persists across iterations

  STAGE_V(0, 0);
  STAGE_U(0, 0);
  if (nchunk > 1) STAGE_V(1, 1);        // outstanding: 12
  asm volatile("s_waitcnt vmcnt(8)" ::: "memory");   // V(0) landed
  asm volatile("s_barrier" ::: "memory");
  __builtin_amdgcn_sched_barrier(0);

  // ---- H(0) + gelu -> bq(0) ----
  {
    const unsigned short* vb = v1s[0];
    fx4 hacc[2][2];
#pragma unroll
    for (int t = 0; t < 2; ++t)
#pragma unroll
      for (int rg = 0; rg < 2; ++rg) hacc[t][rg] = fx4{0.f, 0.f, 0.f, 0.f};
    __builtin_amdgcn_s_setprio(1);
#pragma unroll
    for (int ks = 0; ks < 8; ++ks) {
      int ko = (ks * 32 + hi * 8) ^ vswz;
      bfrag8 vE = *(const bfrag8*)(vb + vbase + ko);
      bfrag8 vO = *(const bfrag8*)(vb + vbase + 4096 + ko);
      hacc[0][0] = __builtin_amdgcn_mfma_f32_16x16x32_bf16(vE, pf[0][ks], hacc[0][0], 0, 0, 0);
      hacc[0][1] = __builtin_amdgcn_mfma_f32_16x16x32_bf16(vE, pf[1][ks], hacc[0][1], 0, 0, 0);
      hacc[1][0] = __builtin_amdgcn_mfma_f32_16x16x32_bf16(vO, pf[0][ks], hacc[1][0], 0, 0, 0);
      hacc[1][1] = __builtin_amdgcn_mfma_f32_16x16x32_bf16(vO, pf[1][ks], hacc[1][1], 0, 0, 0);
    }
    __builtin_amdgcn_s_setprio(0);
    fx4 bE = *(const fx4*)(&b1s[4 * hi]);
    fx4 bO = *(const fx4*)(&b1s[16 + 4 * hi]);
#pragma unroll
    for (int r = 0; r < 4; ++r) {
      bq0[r]     = (short)f2b(gelu_tanh(hacc[0][0][r] + bE[r]));
      bq0[r + 4] = (short)f2b(gelu_tanh(hacc[1][0][r] + bO[r]));
      bq1[r]     = (short)f2b(gelu_tanh(hacc[0][1][r] + bE[r]));
      bq1[r + 4] = (short)f2b(gelu_tanh(hacc[1][1][r] + bO[r]));
    }
  }

  // ---- main pipelined loop: iteration c does Q(c-1) and H(c) ----
  for (int c = 1; c <= nchunk; ++c) {
    asm volatile("s_waitcnt vmcnt(0)" ::: "memory");   // U(c-1) [+V(c)] landed
    asm volatile("s_barrier" ::: "memory");
    __builtin_amdgcn_sched_barrier(0);
    if (c < nchunk) STAGE_U(c, c & 1);                 // into freed u2 half
    if (c + 1 < nchunk) STAGE_V(c + 1, (c + 1) & 1);   // into freed v1 half

    // Q(c-1): consumes bq(c-1) + u2s[(c-1)&1]
    const unsigned short* ub = u2s[(c - 1) & 1];
    __builtin_amdgcn_s_setprio(1);
#pragma unroll
    for (int nt = 0; nt < 16; ++nt) {
      bfrag8 qa = *(const bfrag8*)(ub + (16 * nt + lo) * 32 + qoff);
      qacc[0][nt] = __builtin_amdgcn_mfma_f32_16x16x32_bf16(qa, bq0, qacc[0][nt], 0, 0, 0);
      qacc[1][nt] = __builtin_amdgcn_mfma_f32_16x16x32_bf16(qa, bq1, qacc[1][nt], 0, 0, 0);
    }

    // H(c): independent of Q(c-1) — interleavable by the scheduler
    if (c < nchunk) {
      const unsigned short* vb = v1s[c & 1];
      fx4 hacc[2][2];
#pragma unroll
      for (int t = 0; t < 2; ++t)
#pragma unroll
        for (int rg = 0; rg < 2; ++rg) hacc[t][rg] = fx4{0.f, 0.f, 0.f, 0.f};
#pragma unroll
      for (int ks = 0; ks < 8; ++ks) {
        int ko = (ks * 32 + hi * 8) ^ vswz;
        bfrag8 vE = *(const bfrag8*)(vb + vbase + ko);
        bfrag8 vO = *(const bfrag8*)(vb + vbase + 4096 + ko);
        hacc[0][0] = __builtin_amdgcn_mfma_f32_16x16x32_bf16(vE, pf[0][ks], hacc[0][0], 0, 0, 0);
        hacc[0][1] = __builtin_amdgcn_mfma_f32_16x16x32_bf16(vE, pf[1][ks], hacc[0][1], 0, 0, 0);
        hacc[1][0] = __builtin_amdgcn_mfma_f32_16x16x32_bf16(vO, pf[0][ks], hacc[1][0], 0, 0, 0);
        hacc[1][1] = __builtin_amdgcn_mfma_f32_16x16x32_bf16(vO, pf[1][ks], hacc[1][1], 0, 0, 0);
      }
      __builtin_amdgcn_s_setprio(0);
      fx4 bE = *(const fx4*)(&b1s[c * 32 + 4 * hi]);
      fx4 bO = *(const fx4*)(&b1s[c * 32 + 16 + 4 * hi]);
#pragma unroll
      for (int r = 0; r < 4; ++r) {
        bq0[r]     = (short)f2b(gelu_tanh(hacc[0][0][r] + bE[r]));
        bq0[r + 4] = (short)f2b(gelu_tanh(hacc[1][0][r] + bO[r]));
        bq1[r]     = (short)f2b(gelu_tanh(hacc[0][1][r] + bE[r]));
        bq1[r + 4] = (short)f2b(gelu_tanh(hacc[1][1][r] + bO[r]));
      }
    } else {
      __builtin_amdgcn_s_setprio(0);
    }
  }
#undef STAGE_V
#undef STAGE_U

  // qacc[rg][nt] lane (lo,hi): Q[rowstart+16rg+lo][16nt+4hi+r] -> bf16 qpart
  unsigned short* qp = qpart + (size_t)j * NROWS * RANK;
#pragma unroll
  for (int rg = 0; rg < 2; ++rg) {
    size_t row = (size_t)(rowstart + 16 * rg + lo);
#pragma unroll
    for (int nt = 0; nt < 16; ++nt) {
      usx4 qv;
      qv[0] = f2b(qacc[rg][nt][0]); qv[1] = f2b(qacc[rg][nt][1]);
      qv[2] = f2b(qacc[rg][nt][2]); qv[3] = f2b(qacc[rg][nt][3]);
      *(usx4*)(qp + row * RANK + 16 * nt + 4 * hi) = qv;
    }
  }
}

// ---------------- out = (sum_j Qpart_j) @ V2 + b2 ----------------
// grid (256, 2), 512 thr; wave = 32 rows x 128 cols; 16B qpart loads.
__global__ __launch_bounds__(512, 4) void ogemm(
    const unsigned short* __restrict__ qpart, int F,   // [F][NROWS][RANK] bf16
    const unsigned short* __restrict__ v2t,            // [D_MODEL][RANK]
    const float* __restrict__ b2,
    float* __restrict__ out)
{
  __shared__ unsigned short Qs[64 * PSTR];
  const int tid = threadIdx.x;
  const int w = tid >> 6, lane = tid & 63, lo = lane & 15, hi = lane >> 4;
  const int wm = w >> 2, wn = w & 3;          // wave grid 2x4
  const size_t gr0 = (size_t)blockIdx.x * 64;
  const int n0 = blockIdx.y * 512 + wn * 128;

#pragma unroll
  for (int it = 0; it < 4; ++it) {            // 64x256 elems / 8-per-thread
    int idx = it * 512 + tid;
    int r = idx >> 5, c = (idx & 31) << 3;
    float s[8] = {0.f, 0.f, 0.f, 0.f, 0.f, 0.f, 0.f, 0.f};
    for (int jj = 0; jj < F; ++jj) {
      bfrag8 q = *(const bfrag8*)(qpart + (size_t)jj * NROWS * RANK + (gr0 + r) * RANK + c);
#pragma unroll
      for (int k = 0; k < 8; ++k) s[k] += b2f((unsigned short)q[k]);
    }
    usx4 v0, v1;
#pragma unroll
    for (int k = 0; k < 4; ++k) { v0[k] = f2b(s[k]); v1[k] = f2b(s[k + 4]); }
    *(usx4*)(Qs + r * PSTR + c)     = v0;
    *(usx4*)(Qs + r * PSTR + c + 4) = v1;
  }
  __syncthreads();

  fx4 acc[2][8];
#pragma unroll
  for (int mt = 0; mt < 2; ++mt)
#pragma unroll
    for (int nt = 0; nt < 8; ++nt) acc[mt][nt] = fx4{0.f, 0.f, 0.f, 0.f};

#pragma unroll
  for (int ks = 0; ks < RANK; ks += 32) {
    bfrag8 a[2], b[8];
#pragma unroll
    for (int mt = 0; mt < 2; ++mt)
      a[mt] = *(const bfrag8*)(Qs + (wm * 32 + 16 * mt + lo) * PSTR + ks + hi * 8);
#pragma unroll
    for (int nt = 0; nt < 8; ++nt)
      b[nt] = *(const bfrag8*)(v2t + (size_t)(n0 + nt * 16 + lo) * RANK + ks + hi * 8);
#pragma unroll
    for (int mt = 0; mt < 2; ++mt)
#pragma unroll
      for (int nt = 0; nt < 8; ++nt)
        acc[mt][nt] = __builtin_amdgcn_mfma_f32_16x16x32_bf16(a[mt], b[nt], acc[mt][nt], 0, 0, 0);
  }

#pragma unroll
  for (int nt = 0; nt < 8; ++nt) {
    int col = n0 + nt * 16 + lo;
    float bias = b2[col];
#pragma unroll
    for (int mt = 0; mt < 2; ++mt)
#pragma unroll
      for (int r = 0; r < 4; ++r)
        out[(gr0 + wm * 32 + 16 * mt + 4 * hi + r) * D_MODEL + col] = acc[mt][nt][r] + bias;
  }
}

extern "C" void kernel_launch(void* const* d_in, const int* in_sizes, int n_in,
                              void* d_out, int out_size, void* d_ws, size_t ws_size,
                              hipStream_t stream) {
  const float* x  = (const float*)d_in[0];
  const float* U1 = (const float*)d_in[1];
  const float* V1 = (const float*)d_in[2];
  const float* b1 = (const float*)d_in[3];
  const float* U2 = (const float*)d_in[4];
  const float* V2 = (const float*)d_in[5];
  const float* b2 = (const float*)d_in[6];
  float* out = (float*)d_out;

  unsigned short* ws16 = (unsigned short*)d_ws;
  unsigned short* u1t = ws16;                                 // [256][1024]
  unsigned short* v1c = u1t + (size_t)RANK * D_MODEL;         // [4096][256] swz
  unsigned short* u2c = v1c + (size_t)D_FF * RANK;            // [128][256][32] chunked
  unsigned short* v2t = u2c + (size_t)RANK * D_FF;            // [1024][256]
  unsigned short* Pbf = v2t + (size_t)D_MODEL * RANK;         // [16384][256] bf16
  unsigned short* qpart = Pbf + (size_t)NROWS * RANK;         // [F][16384][256] bf16

  size_t fixed_bytes = 2ull * ((size_t)RANK * D_MODEL + (size_t)D_FF * RANK +
                               (size_t)RANK * D_FF + (size_t)D_MODEL * RANK +
                               (size_t)NROWS * RANK);
  size_t qb = (size_t)NROWS * RANK * 2;   // bf16 slice
  int F = (ws_size >= fixed_bytes + 4 * qb) ? 4 : 2;

  packall<<<2560, 256, 0, stream>>>(U1, V1, U2, V2, u1t, v1c, u2c, v2t);
  pgemm<<<NROWS / 32, 256, 0, stream>>>(x, u1t, Pbf);
  hqgemm<<<(NROWS / 128) * F, 256, 0, stream>>>(Pbf, v1c, b1, u2c, qpart, F);
  ogemm<<<dim3(NROWS / 64, D_MODEL / 512), 512, 0, stream>>>(qpart, F, v2t, b2, out);
}